// Round 12
// baseline (70.868 us; speedup 1.0000x reference)
//
#include <hip/hip_runtime.h>
#include <cstdint>

// Problem: B=4, IC=OC=64, H=W=32, K=3, PAD=1
// Outputs: new_x (262144 f32), new_q (262144 f32) concatenated.
//
//   a0 = conv3x3(x,W,pad=1)+bias ; p0 = sigmoid(a0)
//   new_x = 2*(u < p0) - 1,  u = JAX threefry2x32-20, key=(0,42),
//           partitionable counter mode, draw = out0^out1   [verified r2]
//   new_q = 2*new_x*s1*C1   [1st-order Taylor; residual ~1.2e-4 << 2e-2, r7]
//     s1 = p0(1-p0),  C1 = conv3x3(x*q, W)
//
// Round 12 (final squeeze over r11's 70.0us):
//  - main transposes only the 18 columns its nt-half reads (was 34).
//  - wprep packs 4 weights/thread -> dword digit stores (36 blocks, was 144).
//  - hybrid sigmoid: f32 expf fast path, f64 fallback iff |u-p0|<1e-5
//    (decision-identical: a0 exact to 1.3e-7, f32 path err <=5e-7 << 1e-5).
// a0 path EXACT (r2-r11): W as 4 signed radix-256 digits of round(W*2^31),
// x as i8, mfma_i32_16x16x64_i8 (i32 exact), f64 reconstruction.
// Fragment layouts (16x16 family): A[m=lane&15][k=quad*(K/4)+j],
// B[k=quad*(K/4)+j][n=lane&15], C/D col(n)=lane&15, row(m)=quad*4+reg.

typedef __attribute__((ext_vector_type(4))) int   i32x4;
typedef __attribute__((ext_vector_type(8))) short s16x8;
typedef __attribute__((ext_vector_type(4))) float f32x4;

// ---- ws byte offsets (weights only) ----
static constexpr int OFF_WD = 0;        // i8  [dig4][tap9][oc64][ic64] 147,456 B
static constexpr int OFF_WB = 147456;   // bf16[tap9][oc64][ic64]        73,728 B

// LDS strides (per pixel), padded
static constexpr int X8_STRIDE = 80;    // bytes  (64 + 16 pad)
static constexpr int XQ_STRIDE = 72;    // ushorts (64 + 8 pad = 144 B)

__device__ __forceinline__ uint32_t rotl32(uint32_t v, int n) {
  return (v << n) | (v >> (32 - n));
}

__device__ __forceinline__ unsigned short f2bf(float f) {
  uint32_t u = __float_as_uint(f);
  uint32_t r = (u + 0x7FFFu + ((u >> 16) & 1u)) >> 16;   // RNE
  return (unsigned short)r;
}

// JAX threefry2x32-20, key=(0,42), partitionable: counter (0,j), draw=out0^out1
__device__ __forceinline__ float threefry_u(uint32_t j) {
  uint32_t x0 = 0u, x1 = j;
  const uint32_t ks1 = 42u, ks2 = 0x1BD11BDAu ^ 42u;
  x0 += 0u; x1 += ks1;
#define QR(rot) { x0 += x1; x1 = rotl32(x1, rot); x1 ^= x0; }
  QR(13) QR(15) QR(26) QR(6)
  x0 += ks1; x1 += ks2 + 1u;
  QR(17) QR(29) QR(16) QR(24)
  x0 += ks2; x1 += 0u + 2u;
  QR(13) QR(15) QR(26) QR(6)
  x0 += 0u; x1 += ks1 + 3u;
  QR(17) QR(29) QR(16) QR(24)
  x0 += ks1; x1 += ks2 + 4u;
  QR(13) QR(15) QR(26) QR(6)
  x0 += ks2; x1 += 0u + 5u;
#undef QR
  uint32_t bits = x0 ^ x1;
  return __uint_as_float((bits >> 9) | 0x3F800000u) - 1.0f;
}

// ---------------- K1: weight digitization, 4 weights/thread (36 blocks x 256) -------
__global__ __launch_bounds__(256) void wprep_kernel(
    const float* __restrict__ weight, char* __restrict__ ws) {
  const int t  = blockIdx.x * 256 + threadIdx.x;   // < 9216
  const int k0 = t * 4;                            // k = tap*4096 + oc*64 + ic
  const int ic0 = k0 & 63;                         // multiple of 4 -> same oc/tap
  const int kk  = k0 >> 6;
  const int oc  = kk & 63;
  const int tap = kk >> 6;
  const int kh = tap / 3, kw = tap % 3;

  uint32_t dig[4] = {0u, 0u, 0u, 0u};
  unsigned short bf[4];
#pragma unroll
  for (int j = 0; j < 4; ++j) {
    float Wv = weight[(oc * 64 + ic0 + j) * 9 + kh * 3 + kw];
    long long wi = llrint((double)Wv * 2147483648.0);  // round(W*2^31), |wi|<2^28
#pragma unroll
    for (int d = 0; d < 4; ++d) {
      signed char c = (signed char)(wi & 0xFF);        // balanced low byte
      dig[d] |= ((uint32_t)(unsigned char)c) << (8 * j);
      wi = (wi - (long long)c) >> 8;
    }
    bf[j] = f2bf(Wv);
  }
  char* wd = ws + OFF_WD;
#pragma unroll
  for (int d = 0; d < 4; ++d)
    *(uint32_t*)(wd + d * 36864 + k0) = dig[d];
  *(uint2*)(((unsigned short*)(ws + OFF_WB)) + k0) =
      make_uint2((uint32_t)bf[0] | ((uint32_t)bf[1] << 16),
                 (uint32_t)bf[2] | ((uint32_t)bf[3] << 16));
}

// ---------------- K2: 18-col halo->LDS transpose + MFMA + hybrid epilogue -----------
// grid 256 = (b*32 + h)*2 + nt ; block 256 = 4 waves, wave = oc-tile (16 oc)
__global__ __launch_bounds__(256, 1) void main_kernel(
    const float* __restrict__ x, const float* __restrict__ q,
    const char* __restrict__ ws, const float* __restrict__ bias,
    float* __restrict__ out) {
  const char* wd           = ws + OFF_WD;
  const unsigned short* wb = (const unsigned short*)(ws + OFF_WB);

  __shared__ __align__(16) char           x8s[3 * 34 * X8_STRIDE];   // 8,160 B
  __shared__ __align__(16) unsigned short xqs[3 * 34 * XQ_STRIDE];   // 14,688 B

  const int b  = blockIdx.x >> 6;
  const int h  = (blockIdx.x >> 1) & 31;
  const int nt = blockIdx.x & 1;
  const int tid = threadIdx.x;

  // ---- zero LDS (covers borders + padding) ----
  {
    int* z1 = (int*)x8s;
#pragma unroll
    for (int i = tid; i < 3 * 34 * X8_STRIDE / 4; i += 256) z1[i] = 0;
    int* z2 = (int*)xqs;
#pragma unroll
    for (int i = tid; i < 3 * 34 * XQ_STRIDE / 2; i += 256) z2[i] = 0;
  }
  __syncthreads();

  // ---- halo transpose, only the 18 needed columns ----
  // nt=0 reads padded wp in [0,17] -> src w 0..16 : chunks {0,8,16}
  // nt=1 reads padded wp in [16,33] -> src w 15..31 : chunks {8,16,24}
  {
    const int ic = tid >> 2;
    const int c  = tid & 3;
    if (c < 3) {
      const int w0 = nt * 8 + c * 8;
#pragma unroll
      for (int r = 0; r < 3; ++r) {
        const int hg = h - 1 + r;
        if (hg >= 0 && hg < 32) {
          const int src = ((b * 64 + ic) * 32 + hg) * 32 + w0;
          float4 xa = *(const float4*)(x + src);
          float4 xb = *(const float4*)(x + src + 4);
          float4 qa = *(const float4*)(q + src);
          float4 qb = *(const float4*)(q + src + 4);
          float xv[8] = {xa.x, xa.y, xa.z, xa.w, xb.x, xb.y, xb.z, xb.w};
          float qv[8] = {qa.x, qa.y, qa.z, qa.w, qb.x, qb.y, qb.z, qb.w};
#pragma unroll
          for (int j = 0; j < 8; ++j) {
            const int wp = w0 + j + 1;   // interior 1..32
            x8s[(r * 34 + wp) * X8_STRIDE + ic] = (char)(int)xv[j];
            xqs[(r * 34 + wp) * XQ_STRIDE + ic] = f2bf(xv[j] * qv[j]);
          }
        }
      }
    }
  }
  __syncthreads();

  const int octile = tid >> 6;
  const int lane   = tid & 63;
  const int quad   = lane >> 4;
  const int l16    = lane & 15;

  // ---- preload all 9 B-fragment sets from LDS ----
  const int pxbase = nt * 16 + l16;
  i32x4 bI[9];
  s16x8 bX[9][2];
#pragma unroll
  for (int kh = 0; kh < 3; ++kh) {
#pragma unroll
    for (int kw = 0; kw < 3; ++kw) {
      const int t = kh * 3 + kw;
      const int px = kh * 34 + pxbase + kw;
      bI[t]    = *(const i32x4*)&x8s[px * X8_STRIDE + quad * 16];
      bX[t][0] = *(const s16x8*)&xqs[px * XQ_STRIDE + quad * 8];
      bX[t][1] = *(const s16x8*)&xqs[px * XQ_STRIDE + 32 + quad * 8];
    }
  }

  i32x4 accI[4];
#pragma unroll
  for (int d = 0; d < 4; ++d) accI[d] = (i32x4){0, 0, 0, 0};
  f32x4 aC1 = {0.f, 0.f, 0.f, 0.f};

  const int aoff_i8 = (octile * 16 + l16) * 64 + quad * 16;   // bytes
  const int aoff_bf = (octile * 16 + l16) * 64 + quad * 8;    // ushort elems

#pragma unroll
  for (int tap = 0; tap < 9; ++tap) {
    i32x4 aI[4];
#pragma unroll
    for (int d = 0; d < 4; ++d)
      aI[d] = *(const i32x4*)(wd + d * 36864 + tap * 4096 + aoff_i8);
    s16x8 aW0 = *(const s16x8*)(wb + tap * 4096 + aoff_bf);
    s16x8 aW1 = *(const s16x8*)(wb + tap * 4096 + aoff_bf + 32);
#pragma unroll
    for (int d = 0; d < 4; ++d)
      accI[d] = __builtin_amdgcn_mfma_i32_16x16x64_i8(aI[d], bI[tap], accI[d], 0, 0, 0);
    aC1 = __builtin_amdgcn_mfma_f32_16x16x32_bf16(aW0, bX[tap][0], aC1, 0, 0, 0);
    aC1 = __builtin_amdgcn_mfma_f32_16x16x32_bf16(aW1, bX[tap][1], aC1, 0, 0, 0);
  }

  // ---- epilogue: hybrid sigmoid. C/D col(n=px)=l16, row(m=oc)=quad*4+r ----
  const int w = nt * 16 + l16;
#pragma unroll
  for (int r = 0; r < 4; ++r) {
    const int ocr = octile * 16 + quad * 4 + r;
    double a0 = (((double)accI[3][r] * 256.0 + (double)accI[2][r]) * 256.0 +
                 (double)accI[1][r]) * 256.0 + (double)accI[0][r];
    a0 = a0 * (1.0 / 2147483648.0) + (double)bias[ocr];
    const int o = ((b * 64 + ocr) * 32 + h) * 32 + w;
    float su = threefry_u((uint32_t)o);
    float p0 = 1.0f / (1.0f + expf(-(float)a0));
    float diff = su - p0;
    float nx;
    if (__builtin_expect(fabsf(diff) >= 1e-5f, 1)) {
      nx = (diff < 0.0f) ? 1.0f : -1.0f;
    } else {
      // rare: exact f64 decision (identical to r2-r11 proven path)
      double p0d = 1.0 / (1.0 + exp(-a0));
      nx = ((double)su < p0d) ? 1.0f : -1.0f;
    }
    float s1 = p0 * (1.0f - p0);
    float dq = 2.0f * nx * s1 * aC1[r];
    out[o] = nx;
    out[262144 + o] = dq;
  }
}

extern "C" void kernel_launch(void* const* d_in, const int* in_sizes, int n_in,
                              void* d_out, int out_size, void* d_ws, size_t ws_size,
                              hipStream_t stream) {
  const float* x      = (const float*)d_in[0];
  const float* q      = (const float*)d_in[1];
  const float* weight = (const float*)d_in[2];
  const float* bias   = (const float*)d_in[3];
  float* out = (float*)d_out;
  char* ws   = (char*)d_ws;

  // K1: 9216 threads x 4 weights = 36864 weights, 36 blocks
  wprep_kernel<<<36, 256, 0, stream>>>(weight, ws);
  // K2: 256 blocks x 256; 18-col halo transpose in-kernel, B from LDS
  main_kernel<<<256, 256, 0, stream>>>(x, q, ws, bias, out);
}